// Round 4
// baseline (564.317 us; speedup 1.0000x reference)
//
#include <hip/hip_runtime.h>

// Conv2d VALID 3x3: x[32][64][112][112] f32, w[128][64][3][3] f32 -> out[32][128][110][110] f32
// Implicit GEMM on bf16 MFMA 16x16x32.
// R7: PERSISTENT double-buffered blocks. R6 showed TLP is not the lever (occupancy 2x -> MfmaUtil
//     +2pts): per-block serial phases dominate and scale with block count. Now grid=256 (1/CU),
//     512 thr / 8 waves, xwin[2] ping-pong (93.3 KB LDS), 6-7 tiles per block. Per tile:
//     STAGE_LOAD(next)->regs issued BEFORE the K-loop (T14: HBM latency hides under MFMA);
//     EPILOGUE(prev) stores issued before the K-loop (drain hides under MFMA);
//     K-loop (R4-proven barrier-free shape, W from L2); STAGE_WRITE(next) after; ONE barrier/tile.
//     launch_bounds(512,2) -> 256 regs/wave: room for staged regs + af/bfrag pipelining.

typedef short bf16x8 __attribute__((ext_vector_type(8)));
typedef float f32x4 __attribute__((ext_vector_type(4)));

__device__ __forceinline__ unsigned short f2bf(float f) {
    unsigned int u = __builtin_bit_cast(unsigned int, f);
    unsigned int r = u + 0x7fffu + ((u >> 16) & 1u);   // RNE
    return (unsigned short)(r >> 16);
}
__device__ __forceinline__ unsigned int pack2(float lo, float hi) {
    return (unsigned)f2bf(lo) | ((unsigned)f2bf(hi) << 16);
}

// wp layout (bf16x8 units of 16B): unit = ((r*8 + cog)*2 + cs)*64 + lane, lane = quad*16 + l15.
// wp[unit*8 + e] = bf16(W[co = cog*16 + l15][ci = cs*32 + quad*8 + e][kh = r/3][kw = r%3])
// -> a wave's fragment load for (r, cog, cs) is one contiguous 1024 B global_load_dwordx4.
__global__ void wperm_kernel(const float* __restrict__ W, unsigned short* __restrict__ wp) {
    int t = blockIdx.x * 256 + threadIdx.x;
    if (t < 73728) {
        int e    = t & 7;
        int l15  = (t >> 3) & 15;
        int quad = (t >> 7) & 3;
        int cs   = (t >> 9) & 1;
        int cog  = (t >> 10) & 7;
        int r    = t >> 13;
        int ci = cs * 32 + quad * 8 + e;
        int co = cog * 16 + l15;
        wp[t] = f2bf(W[(co * 64 + ci) * 9 + r]);
    }
}

#define XWIN_SH 23328   // 324 px * 72 shorts (18x18 window, row stride 72 = conflict-free)

__global__ __launch_bounds__(512, 2) void conv_mfma(const float* __restrict__ x,
                                                    const unsigned short* __restrict__ wp,
                                                    float* __restrict__ out) {
    __shared__ alignas(16) unsigned short xwin[2 * XWIN_SH];   // 93312 B -> 1 block/CU

    const int tid  = threadIdx.x;
    const int lane = tid & 63;
    const int wv   = tid >> 6;          // 0..7
    const int quad = lane >> 4;
    const int l15  = lane & 15;
    const int wco  = wv >> 2;           // 0..1 : co half (64 co each)
    const int woh  = wv & 3;            // 0..3 : 4 oh rows each

    // persistent mapping: xcd = blk&7 owns batches {xcd, xcd+8, xcd+16, xcd+24};
    // 196 tiles per XCD spread over 32 block-slots; slots 0..3 run 7 tiles, rest 6.
    const int blk    = blockIdx.x;      // 256
    const int xcd    = blk & 7;
    const int slot   = blk >> 3;        // 0..31
    const int ntiles = (slot < 4) ? 7 : 6;

    // ---- staged-tile register state (held across the K-loop; T14) ----
    f32x4 sa[5], sc[5];
    float hx[8];

    auto stage_load = [&](int b, int oh0, int ow0) {
        const float* xb = x + b * 802816;                   // 64*12544
        #pragma unroll
        for (int s = 0; s < 5; s++) {
            const int t = tid + s * 512;                    // 2304 main items
            if (s < 4 || tid < 256) {
                const int cg = (((t >> 6) & 3) << 3) | (t & 7);
                const int hw = ((t >> 8) << 3) | ((t >> 3) & 7);
                const int hh = hw >> 2;                     // 0..17
                const int wc = hw & 3;
                const int h  = min(oh0 + hh, 111);          // clamped rows feed discarded oh only
                const float* p0 = xb + 2 * cg * 12544 + h * 112 + ow0 + wc * 4;
                sa[s] = *reinterpret_cast<const f32x4*>(p0);
                sc[s] = *reinterpret_cast<const f32x4*>(p0 + 12544);
            }
        }
        #pragma unroll
        for (int s = 0; s < 2; s++) {
            const int u = tid + s * 512;                    // 576 halo items (cols 16,17)
            if (s == 0 || tid < 64) {
                const int cg  = u & 31;
                const int hh  = u >> 5;                     // 0..17
                const int h   = min(oh0 + hh, 111);
                const int w16 = min(ow0 + 16, 111);
                const int w17 = min(ow0 + 17, 111);
                const float* p0 = xb + 2 * cg * 12544 + h * 112;
                hx[s * 4 + 0] = p0[w16];
                hx[s * 4 + 1] = p0[12544 + w16];
                hx[s * 4 + 2] = p0[w17];
                hx[s * 4 + 3] = p0[12544 + w17];
            }
        }
    };

    auto stage_write = [&](int buf) {
        unsigned short* xw = xwin + buf * XWIN_SH;
        #pragma unroll
        for (int s = 0; s < 5; s++) {
            const int t = tid + s * 512;
            if (s < 4 || tid < 256) {
                const int cg = (((t >> 6) & 3) << 3) | (t & 7);
                const int hw = ((t >> 8) << 3) | ((t >> 3) & 7);
                const int hh = hw >> 2;
                const int wc = hw & 3;
                unsigned int* dst = reinterpret_cast<unsigned int*>(
                    &xw[(hh * 18 + wc * 4) * 72 + 2 * cg]);
                dst[0]   = pack2(sa[s][0], sc[s][0]);
                dst[36]  = pack2(sa[s][1], sc[s][1]);
                dst[72]  = pack2(sa[s][2], sc[s][2]);
                dst[108] = pack2(sa[s][3], sc[s][3]);
            }
        }
        #pragma unroll
        for (int s = 0; s < 2; s++) {
            const int u = tid + s * 512;
            if (s == 0 || tid < 64) {
                const int cg = u & 31;
                const int hh = u >> 5;
                unsigned int* dst = reinterpret_cast<unsigned int*>(
                    &xw[(hh * 18 + 16) * 72 + 2 * cg]);
                dst[0]  = pack2(hx[s * 4 + 0], hx[s * 4 + 1]);
                dst[36] = pack2(hx[s * 4 + 2], hx[s * 4 + 3]);
            }
        }
    };

    f32x4 acc[4][4];
    const f32x4 zero = {0.0f, 0.0f, 0.0f, 0.0f};

    auto epilogue = [&](int b, int eoh0, int eow0) {
        // D col(n=ow)=lane&15, row=quad*4+reg
        const int owc = eow0 + l15;
        if (owc < 110) {
            float* ob = out + b * 1548800 + wco * 64 * 12100;   // 128*12100 per batch
            #pragma unroll
            for (int mt = 0; mt < 4; mt++) {
                #pragma unroll
                for (int nt = 0; nt < 4; nt++) {
                    const int oh = eoh0 + woh * 4 + nt;
                    if (oh < 110) {
                        #pragma unroll
                        for (int reg = 0; reg < 4; reg++) {
                            const int co = mt * 16 + quad * 4 + reg;
                            ob[(co * 110 + oh) * 110 + owc] = acc[mt][nt][reg];
                        }
                    }
                }
            }
        }
    };

    // per-thread W base: fragment (r, cog, cs) lives at wq[((r*8+cog)*2+cs)*64]
    const bf16x8* wq = reinterpret_cast<const bf16x8*>(wp) + lane;
    const int cogb = wco * 4;

    // ---- prologue: stage tile 0 directly ----
    {
        const int t0 = slot;
        const int b0 = xcd + 8 * (t0 / 49);
        const int tl = t0 % 49;
        stage_load(b0, (tl / 7) * 16, (tl % 7) * 16);
        stage_write(0);
    }
    __syncthreads();

    int cur = 0;
    int pb = 0, poh = 0, pow_ = 0;

    for (int j = 0; j < ntiles; j++) {
        const int ti  = slot + 32 * j;
        const int cb  = xcd + 8 * (ti / 49);
        const int ct  = ti % 49;
        const int coh = (ct / 7) * 16;
        const int cow = (ct % 7) * 16;

        const int ni = ti + 32;
        if (ni < 196) {                 // issue next tile's global loads (hide under K-loop)
            const int nb  = xcd + 8 * (ni / 49);
            const int ntl = ni % 49;
            stage_load(nb, (ntl / 7) * 16, (ntl % 7) * 16);
        }
        if (j > 0) epilogue(pb, poh, pow_);   // prev tile's stores drain under this K-loop

        #pragma unroll
        for (int mt = 0; mt < 4; mt++)
            #pragma unroll
            for (int nt = 0; nt < 4; nt++) acc[mt][nt] = zero;

        const unsigned short* xw = xwin + cur * XWIN_SH;
        #pragma unroll
        for (int r = 0; r < 9; r++) {
            const int kh = r / 3;
            const int kw = r % 3;
            #pragma unroll
            for (int cs = 0; cs < 2; cs++) {
                const int ko = cs * 32 + quad * 8;
                bf16x8 af[4];
                #pragma unroll
                for (int mt = 0; mt < 4; mt++)
                    af[mt] = wq[((r * 8 + cogb + mt) * 2 + cs) * 64];   // coalesced 1KB, L1/L2
                bf16x8 bfrag[4];
                #pragma unroll
                for (int nt = 0; nt < 4; nt++)
                    bfrag[nt] = *reinterpret_cast<const bf16x8*>(
                        &xw[((woh * 4 + nt + kh) * 18 + (l15 + kw)) * 72 + ko]);
                __builtin_amdgcn_s_setprio(1);
                #pragma unroll
                for (int mt = 0; mt < 4; mt++)
                    #pragma unroll
                    for (int nt = 0; nt < 4; nt++)
                        acc[mt][nt] = __builtin_amdgcn_mfma_f32_16x16x32_bf16(
                            af[mt], bfrag[nt], acc[mt][nt], 0, 0, 0);
                __builtin_amdgcn_s_setprio(0);
            }
        }

        if (ni < 196) stage_write(cur ^ 1);   // vmcnt long satisfied; pack2 + ds_write only
        __syncthreads();                      // publish buf^1; one barrier per tile
        pb = cb; poh = coh; pow_ = cow;
        cur ^= 1;
    }
    epilogue(pb, poh, pow_);                  // last tile

}

extern "C" void kernel_launch(void* const* d_in, const int* in_sizes, int n_in,
                              void* d_out, int out_size, void* d_ws, size_t ws_size,
                              hipStream_t stream) {
    const float* x = (const float*)d_in[0];
    const float* W = (const float*)d_in[1];
    float* out = (float*)d_out;
    unsigned short* wp = (unsigned short*)d_ws;             // 147456 B

    wperm_kernel<<<288, 256, 0, stream>>>(W, wp);
    conv_mfma<<<256, 512, 0, stream>>>(x, wp, out);
}

// Round 6
// 512.233 us; speedup vs baseline: 1.1017x; 1.1017x over previous
//
#include <hip/hip_runtime.h>
#include <stdint.h>

// Conv2d VALID 3x3: x[32][64][112][112] f32, w[128][64][3][3] f32 -> out[32][128][110][110] f32
// Implicit GEMM on bf16 MFMA 16x16x32.
// R9 (= R8 cleaned; R8 never ran - container failure): persistent double-buffered blocks with
//     global_load_lds DMA staging (zero register footprint; R7's reg-staging spilled to scratch).
//     Prepass converts x to bf16 channel-last XOR-swizzled layout xswz[b][h][w][c^(w&7)][8ch]:
//     (a) gload_lds dest stays LINEAR (rule 21), (b) ds_read_b128 of a pixel-column is
//     bank-conflict-free (T2 swizzle lives in the global layout), (c) conv reads bf16 = half
//     the x bytes. 256 persistent blocks, xwin[2] ping-pong (84 KB), per tile:
//     stage(next) DMA -> epilogue(prev) stores -> barrier-free R4 K-loop -> ONE __syncthreads.
//     Fallback to the proven R4 kernel if ws_size can't hold the 51.4 MB xswz.

typedef short bf16x8 __attribute__((ext_vector_type(8)));
typedef float f32x4 __attribute__((ext_vector_type(4)));

__device__ __forceinline__ unsigned short f2bf(float f) {
    unsigned int u = __builtin_bit_cast(unsigned int, f);
    unsigned int r = u + 0x7fffu + ((u >> 16) & 1u);   // RNE
    return (unsigned short)(r >> 16);
}
__device__ __forceinline__ unsigned int pack2(float lo, float hi) {
    return (unsigned)f2bf(lo) | ((unsigned)f2bf(hi) << 16);
}

// wp layout (bf16x8 units of 16B): unit = ((r*8 + cog)*2 + cs)*64 + lane, lane = quad*16 + l15.
// wp[unit*8 + e] = bf16(W[co = cog*16 + l15][ci = cs*32 + quad*8 + e][kh = r/3][kw = r%3])
__global__ void wperm_kernel(const float* __restrict__ W, unsigned short* __restrict__ wp) {
    int t = blockIdx.x * 256 + threadIdx.x;
    if (t < 73728) {
        int e    = t & 7;
        int l15  = (t >> 3) & 15;
        int quad = (t >> 7) & 3;
        int cs   = (t >> 9) & 1;
        int cog  = (t >> 10) & 7;
        int r    = t >> 13;
        int ci = cs * 32 + quad * 8 + e;
        int co = cog * 16 + l15;
        wp[t] = f2bf(W[(co * 64 + ci) * 9 + r]);
    }
}

// Prepass: xswz[b][h][w][c][e] (shorts) = bf16(x[b][ci = (c ^ (w&7))*8 + e][h][w]).
// One block per (b,h) row; LDS 112x33-u32 padded transpose; coalesced f32 reads (along w),
// coalesced 16B writes (linear in (w,c)).
__global__ __launch_bounds__(256) void xconv_kernel(const float* __restrict__ x,
                                                    unsigned short* __restrict__ xswz) {
    __shared__ unsigned int row32[112 * 33];            // 14784 B
    const int bh = blockIdx.x;                          // b*112 + h
    const int b  = bh / 112;
    const int h  = bh - b * 112;
    const float* xb = x + (size_t)b * 802816 + h * 112; // + ci*12544 + w
    for (int t = threadIdx.x; t < 3584; t += 256) {
        const int cg = t / 112;                         // 0..31 (ci pair 2cg,2cg+1)
        const int w  = t - cg * 112;
        const float lo = xb[(2 * cg) * 12544 + w];
        const float hi = xb[(2 * cg) * 12544 + 12544 + w];
        row32[w * 33 + cg] = pack2(lo, hi);             // stride 33: conflict-free
    }
    __syncthreads();
    unsigned short* ob = xswz + (size_t)bh * 7168;      // 112 px * 64 ch
    for (int t = threadIdx.x; t < 896; t += 256) {
        const int wl  = t >> 3;
        const int c   = t & 7;
        const int cg0 = (c ^ (wl & 7)) * 4;             // 4 u32 = 8 channels
        uint4 v;
        v.x = row32[wl * 33 + cg0 + 0];
        v.y = row32[wl * 33 + cg0 + 1];
        v.z = row32[wl * 33 + cg0 + 2];
        v.w = row32[wl * 33 + cg0 + 3];
        *reinterpret_cast<uint4*>(ob + t * 8) = v;      // linear 16B: fully coalesced
    }
}

#define XW_SH   20992   // shorts per buffer: 18*18 px * 64ch = 20736 + 256 slack (41984 B)
#define NCHUNK  2592    // 324 px * 8 chunks of 16 B

__global__ __launch_bounds__(512, 2) void conv_mfma_dl(const unsigned short* __restrict__ xswz,
                                                       const unsigned short* __restrict__ wp,
                                                       float* __restrict__ out) {
    __shared__ alignas(16) unsigned short xwin[2 * XW_SH];   // 83968 B -> 1 block/CU

    const int tid  = threadIdx.x;
    const int lane = tid & 63;
    const int wv   = tid >> 6;          // 0..7
    const int quad = lane >> 4;
    const int l15  = lane & 15;
    const int wco  = wv >> 2;           // 0..1 : co half (64 co each)
    const int woh  = wv & 3;            // 0..3 : 4 oh rows each

    // persistent: xcd = blk&7 owns batches {xcd, xcd+8, xcd+16, xcd+24}; 196 tiles over 32 slots
    const int blk    = blockIdx.x;      // 256
    const int xcd    = blk & 7;
    const int slot   = blk >> 3;        // 0..31
    const int ntiles = (slot < 4) ? 7 : 6;

    // ---- stage tile ti into buf via global_load_lds (zero register footprint) ----
    auto stage = [&](int ti, int buf) {
        const int b   = xcd + 8 * (ti / 49);
        const int tl  = ti % 49;
        const int oh0 = (tl / 7) * 16;
        const int ow0 = (tl % 7) * 16;
        const unsigned short* xbase = xswz + (size_t)b * 802816;
        #pragma unroll
        for (int it = 0; it < 6; ++it) {
            const int cb = it * 512 + wv * 64;          // wave-uniform chunk base
            const int ch = cb + lane;
            if (ch < NCHUNK) {                          // tail: partial wave masked
                const int pxc = ch >> 3;                // 0..323
                const int c   = ch & 7;
                const int hh  = pxc / 18;
                const int col = pxc - hh * 18;
                const int h   = min(oh0 + hh, 111);     // clamped rows feed discarded oh only
                const int w   = min(ow0 + col, 111);    // clamped cols feed discarded ow only
                // unclamped: w&7 == col&7 -> chunk c holds channels (c^(col&7))*8, exactly
                // what the swizzled ds_read expects. Clamped: garbage, never read as valid.
                __builtin_amdgcn_global_load_lds(
                    (const __attribute__((address_space(1))) unsigned int*)
                        (xbase + ((h * 112 + w) << 6) + c * 8),
                    (__attribute__((address_space(3))) unsigned int*)
                        (&xwin[buf * XW_SH + cb * 8]),
                    16, 0, 0);
            }
        }
    };

    f32x4 acc[4][4];
    const f32x4 zero = {0.0f, 0.0f, 0.0f, 0.0f};

    auto epilogue = [&](int ti) {
        const int b   = xcd + 8 * (ti / 49);
        const int tl  = ti % 49;
        const int oh0 = (tl / 7) * 16;
        const int ow0 = (tl % 7) * 16;
        const int owc = ow0 + l15;
        if (owc < 110) {
            float* ob = out + b * 1548800 + wco * 64 * 12100;
            #pragma unroll
            for (int mt = 0; mt < 4; mt++) {
                #pragma unroll
                for (int nt = 0; nt < 4; nt++) {
                    const int oh = oh0 + woh * 4 + nt;
                    if (oh < 110) {
                        #pragma unroll
                        for (int reg = 0; reg < 4; reg++) {
                            const int co = mt * 16 + quad * 4 + reg;
                            ob[(co * 110 + oh) * 110 + owc] = acc[mt][nt][reg];
                        }
                    }
                }
            }
        }
    };

    // per-thread W base: fragment (r, cog, cs) lives at wq[((r*8+cog)*2+cs)*64]
    const bf16x8* wq = reinterpret_cast<const bf16x8*>(wp) + lane;
    const int cogb = wco * 4;

    // ---- prologue ----
    stage(slot, 0);
    __syncthreads();                    // implicit vmcnt(0): prologue DMA drained

    int cur = 0;
    int pti = -1;

    for (int j = 0; j < ntiles; j++) {
        const int ti = slot + 32 * j;
        const int ni = ti + 32;
        if (ni < 196) stage(ni, cur ^ 1);   // DMA runs under this tile's K-loop
        if (pti >= 0) epilogue(pti);        // prev stores drain under this K-loop

        #pragma unroll
        for (int mt = 0; mt < 4; mt++)
            #pragma unroll
            for (int nt = 0; nt < 4; nt++) acc[mt][nt] = zero;

        const unsigned short* xw = xwin + cur * XW_SH;
        #pragma unroll
        for (int r = 0; r < 9; r++) {
            const int kh = r / 3;
            const int kw = r % 3;
            const int col = l15 + kw;
            #pragma unroll
            for (int cs = 0; cs < 2; cs++) {
                bf16x8 af[4];
                #pragma unroll
                for (int mt = 0; mt < 4; mt++)
                    af[mt] = wq[((r * 8 + cogb + mt) * 2 + cs) * 64];   // 1KB coalesced, L2
                const int sl = ((cs * 4 + quad) ^ (col & 7)) * 8;       // un-swizzle on read
                bf16x8 bfrag[4];
                #pragma unroll
                for (int nt = 0; nt < 4; nt++)
                    bfrag[nt] = *reinterpret_cast<const bf16x8*>(
                        &xw[((woh * 4 + nt + kh) * 18 + col) * 64 + sl]);
                __builtin_amdgcn_s_setprio(1);
                #pragma unroll
                for (int mt = 0; mt < 4; mt++)
                    #pragma unroll
                    for (int nt = 0; nt < 4; nt++)
                        acc[mt][nt] = __builtin_amdgcn_mfma_f32_16x16x32_bf16(
                            af[mt], bfrag[nt], acc[mt][nt], 0, 0, 0);
                __builtin_amdgcn_s_setprio(0);
            }
        }

        __syncthreads();    // publish buf^1 (DMA long done); one barrier per tile
        pti = ti;
        cur ^= 1;
    }
    epilogue(pti);
}

// ---------------- R4 fallback (proven, 353 us): used when ws can't hold xswz --------------
__global__ __launch_bounds__(512, 4) void conv_mfma_r4(const float* __restrict__ x,
                                                       const unsigned short* __restrict__ wp,
                                                       float* __restrict__ out) {
    __shared__ alignas(16) unsigned short xwin[324 * 72];

    const int tid  = threadIdx.x;
    const int lane = tid & 63;
    const int wv   = tid >> 6;
    const int quad = lane >> 4;
    const int l15  = lane & 15;
    const int wco  = wv >> 2;
    const int woh  = wv & 3;

    const int blk  = blockIdx.x;
    const int xcd  = blk & 7;
    const int slot = blk >> 3;
    const int b    = xcd + 8 * (slot / 49);
    const int tile = slot % 49;
    const int oh0  = (tile / 7) * 16;
    const int ow0  = (tile % 7) * 16;

    const float* xb = x + b * 802816;

    for (int t = tid; t < 2304; t += 512) {
        const int cg = (((t >> 6) & 3) << 3) | (t & 7);
        const int hw = ((t >> 8) << 3) | ((t >> 3) & 7);
        const int hh = hw >> 2;
        const int wc = hw & 3;
        const int h  = min(oh0 + hh, 111);
        const float* p0 = xb + 2 * cg * 12544 + h * 112 + ow0 + wc * 4;
        const f32x4 a = *reinterpret_cast<const f32x4*>(p0);
        const f32x4 c = *reinterpret_cast<const f32x4*>(p0 + 12544);
        unsigned int* dst = reinterpret_cast<unsigned int*>(
            &xwin[(hh * 18 + wc * 4) * 72 + 2 * cg]);
        dst[0]   = pack2(a[0], c[0]);
        dst[36]  = pack2(a[1], c[1]);
        dst[72]  = pack2(a[2], c[2]);
        dst[108] = pack2(a[3], c[3]);
    }
    for (int u = tid; u < 576; u += 512) {
        const int cg  = u & 31;
        const int hh  = u >> 5;
        const int h   = min(oh0 + hh, 111);
        const int w16 = min(ow0 + 16, 111);
        const int w17 = min(ow0 + 17, 111);
        const float* p0 = xb + 2 * cg * 12544 + h * 112;
        unsigned int* dst = reinterpret_cast<unsigned int*>(
            &xwin[(hh * 18 + 16) * 72 + 2 * cg]);
        dst[0]  = pack2(p0[w16], p0[12544 + w16]);
        dst[36] = pack2(p0[w17], p0[12544 + w17]);
    }

    f32x4 acc[4][4];
    const f32x4 zero = {0.0f, 0.0f, 0.0f, 0.0f};
    #pragma unroll
    for (int mt = 0; mt < 4; mt++)
        #pragma unroll
        for (int nt = 0; nt < 4; nt++) acc[mt][nt] = zero;

    __syncthreads();

    const bf16x8* wq = reinterpret_cast<const bf16x8*>(wp) + lane;
    const int cogb = wco * 4;

    #pragma unroll
    for (int r = 0; r < 9; r++) {
        const int kh = r / 3;
        const int kw = r % 3;
        #pragma unroll
        for (int cs = 0; cs < 2; cs++) {
            const int ko = cs * 32 + quad * 8;
            bf16x8 af[4];
            #pragma unroll
            for (int mt = 0; mt < 4; mt++)
                af[mt] = wq[((r * 8 + cogb + mt) * 2 + cs) * 64];
            bf16x8 bfrag[4];
            #pragma unroll
            for (int nt = 0; nt < 4; nt++)
                bfrag[nt] = *reinterpret_cast<const bf16x8*>(
                    &xwin[((woh * 4 + nt + kh) * 18 + (l15 + kw)) * 72 + ko]);
            __builtin_amdgcn_s_setprio(1);
            #pragma unroll
            for (int mt = 0; mt < 4; mt++)
                #pragma unroll
                for (int nt = 0; nt < 4; nt++)
                    acc[mt][nt] = __builtin_amdgcn_mfma_f32_16x16x32_bf16(
                        af[mt], bfrag[nt], acc[mt][nt], 0, 0, 0);
            __builtin_amdgcn_s_setprio(0);
        }
    }

    const int owc = ow0 + l15;
    if (owc < 110) {
        float* ob = out + b * 1548800 + wco * 64 * 12100;
        #pragma unroll
        for (int mt = 0; mt < 4; mt++) {
            #pragma unroll
            for (int nt = 0; nt < 4; nt++) {
                const int oh = oh0 + woh * 4 + nt;
                if (oh < 110) {
                    #pragma unroll
                    for (int reg = 0; reg < 4; reg++) {
                        const int co = mt * 16 + quad * 4 + reg;
                        ob[(co * 110 + oh) * 110 + owc] = acc[mt][nt][reg];
                    }
                }
            }
        }
    }
}

extern "C" void kernel_launch(void* const* d_in, const int* in_sizes, int n_in,
                              void* d_out, int out_size, void* d_ws, size_t ws_size,
                              hipStream_t stream) {
    const float* x = (const float*)d_in[0];
    const float* W = (const float*)d_in[1];
    float* out = (float*)d_out;
    unsigned short* wp = (unsigned short*)d_ws;             // 147456 B

    wperm_kernel<<<288, 256, 0, stream>>>(W, wp);

    const size_t XOFF = 147456;                             // 256-aligned
    const size_t XB   = (size_t)32 * 112 * 112 * 64 * 2;    // 51,380,224 B
    if (ws_size >= XOFF + XB) {
        unsigned short* xswz = (unsigned short*)((char*)d_ws + XOFF);
        xconv_kernel<<<32 * 112, 256, 0, stream>>>(x, xswz);
        conv_mfma_dl<<<256, 512, 0, stream>>>(xswz, wp, out);
    } else {
        conv_mfma_r4<<<1568, 512, 0, stream>>>(x, wp, out);
    }
}